// Round 15
// baseline (512.726 us; speedup 1.0000x reference)
//
#include <hip/hip_runtime.h>
#include <hip/hip_bf16.h>
#include <hip/hip_fp16.h>

#define BATCH 16384
#define HID   2048
#define IND   784
#define INDP  896   // 784 padded to 14*64 (even # of 64-wide K-tiles)
#define OUTD  10

typedef _Float16 f16;
typedef __attribute__((ext_vector_type(8))) _Float16 f16x8;
typedef __attribute__((ext_vector_type(4))) _Float16 f16x4;
typedef __attribute__((ext_vector_type(4))) float f32x4;

// ---- fused segmented prep (R13/R14, verified) ------------------------------
struct PrepArgs {
    const float* src[6];
    const void*  mk[6];
    f16*         dst[6];
    long         off4[7];
    int          rin[6], kin[6], kout[6];
};

__global__ void prep_fused(PrepArgs a, long total4) {
    long idx = (long)blockIdx.x * blockDim.x + threadIdx.x;
    if (idx >= total4) return;
    int s = 0;
    #pragma unroll
    for (int i = 1; i < 6; ++i) s += (idx >= a.off4[i]);
    long li = idx - a.off4[s];
    int kout = a.kout[s], kin = a.kin[s], rin = a.rin[s];
    int k4 = kout >> 2;
    int r = (int)(li / k4), c = (int)(li - (long)r * k4) << 2;
    f16x4 o = {};
    if (r < rin && c < kin) {
        float4 v = *(const float4*)(a.src[s] + (size_t)r * kin + c);
        float vv0 = v.x, vv1 = v.y, vv2 = v.z, vv3 = v.w;
        if (a.mk[s]) {
            uint4 m = *(const uint4*)((const unsigned int*)a.mk[s] + (size_t)r * kin + c);
            if (!m.x) vv0 = 0.f; if (!m.y) vv1 = 0.f;
            if (!m.z) vv2 = 0.f; if (!m.w) vv3 = 0.f;
        }
        o[0] = (f16)vv0; o[1] = (f16)vv1; o[2] = (f16)vv2; o[3] = (f16)vv3;
    }
    *(f16x4*)(a.dst[s] + (size_t)r * kout + c) = o;
}

__device__ __forceinline__ void gload_lds16(const f16* g, f16* l) {
    __builtin_amdgcn_global_load_lds(
        (const __attribute__((address_space(1))) unsigned int*)g,
        (__attribute__((address_space(3))) unsigned int*)l,
        16, 0, 0);
}

#define BAR()    __builtin_amdgcn_s_barrier()
#define SCHED()  __builtin_amdgcn_sched_barrier(0)
#define WAITV4() asm volatile("s_waitcnt vmcnt(4)" ::: "memory")
#define WAITV2() asm volatile("s_waitcnt vmcnt(2)" ::: "memory")
#define WAITL0() asm volatile("s_waitcnt lgkmcnt(0)" ::: "memory")

// ---- 256x256 8-phase GEMM, m201-cell port (R15): lockstep + quadrant -------
// Design-space: {straddle,lockstep} x {uniform,quadrant}. R7=lockstep+uniform
// (42%), R14=straddle+uniform (48%); this = lockstep+quadrant = m201's cell
// (62% measured on identical geometry). Geometry: LDS [buf][half][128][64]
// f16 per tensor (full 128B-cacheline staging rows; fixes the 1.35x A
// over-fetch of [256][32] panels). Swizzle: 16B-slot ^= (row&7) both sides
// (<=2-way residual, free per m136). Phases: per K-tile 4 quadrants
// (mh,nh) = (0,0),(0,1),(1,1),(1,0); reads 12/4/8/0 b128 with B held in regs;
// per phase: {reads; stage 1 half-unit; BAR; lgkmcnt(0); setprio(1); 16 MFMA;
// setprio(0); [vmcnt]; BAR}. Stage ledger (re-derived, all reads drained >=1
// phase+barrier before restage; all stages drained before read):
//   ph1: b1.A0(t1)  ph2: b1.A1(t1)  ph3: b0.B0(t2)  ph4: b0.B1(t2)+vmcnt(4)
//   ph5: b0.A0(t2)  ph6: b0.A1(t2)  ph7: b1.B0(t3)  ph8: b1.B1(t3)+vmcnt(2)
template<bool RELU>
__global__ __launch_bounds__(512, 2) void gemm8p(
    const f16* __restrict__ A, const f16* __restrict__ B,
    const float* __restrict__ bias, f16* __restrict__ C,
    int N, int K) {
    __shared__ f16 As[2 * 2 * 128 * 64];   // [buf][half][128][64]
    __shared__ f16 Bs[2 * 2 * 128 * 64];

    int nbn = N >> 8;
    int nwg = gridDim.x;
    int cpx = nwg >> 3;
    int bid = blockIdx.x;
    int swz = (bid & 7) * cpx + (bid >> 3);   // XCD-aware, bijective
    int bm = swz / nbn, bn = swz % nbn;

    int tid = threadIdx.x;
    int w = tid >> 6, lane = tid & 63;
    int wr = w >> 2, wc = w & 3;
    int l15 = lane & 15, l4 = lane >> 4;

    const f16* Ag = A + (size_t)bm * 256 * K;
    const f16* Bg = B + (size_t)bn * 256 * K;

    // staging: issue j covers local rows [j*64+w*8, +8); lane row rr, slot
    // lane&7; pre-swizzled global col-slot = (lane&7) ^ (lane>>3)  (row&7 ==
    // lane>>3 since j*64+w*8 == 0 mod 8). LDS dest wave-uniform, linear.
    int rr = w * 8 + (lane >> 3);
    int gcol = ((lane & 7) ^ (lane >> 3)) * 8;

    auto stageA = [&](int buf, int half, int tk) {
        f16* l = As + (buf * 2 + half) * 8192 + (w * 64) * 8;
        gload_lds16(Ag + (size_t)(half * 128 + rr) * K + tk * 64 + gcol, l);
        gload_lds16(Ag + (size_t)(half * 128 + 64 + rr) * K + tk * 64 + gcol, l + 4096);
    };
    auto stageB = [&](int buf, int half, int tk) {
        f16* l = Bs + (buf * 2 + half) * 8192 + (w * 64) * 8;
        gload_lds16(Bg + (size_t)(half * 128 + rr) * K + tk * 64 + gcol, l);
        gload_lds16(Bg + (size_t)(half * 128 + 64 + rr) * K + tk * 64 + gcol, l + 4096);
    };

    // frag reads: local row lr, 16B-slot (ks*4+l4) ^ (lr&7); lr&7 == l15&7.
    auto ldA = [&](f16x8 (&ar)[8], int buf, int mh) {
        int base = (buf * 2 + wr) * 8192;
        #pragma unroll
        for (int m = 0; m < 4; ++m)
            #pragma unroll
            for (int ks = 0; ks < 2; ++ks) {
                int lr = mh * 64 + m * 16 + l15;
                int slot = (ks * 4 + l4) ^ (lr & 7);
                ar[m * 2 + ks] = *(const f16x8*)(As + base + lr * 64 + slot * 8);
            }
    };
    auto ldB = [&](f16x8 (&br)[4], int buf, int nh) {
        int base = (buf * 2 + (wc >> 1)) * 8192;
        #pragma unroll
        for (int n = 0; n < 2; ++n)
            #pragma unroll
            for (int ks = 0; ks < 2; ++ks) {
                int lr = (wc & 1) * 64 + nh * 32 + n * 16 + l15;
                int slot = (ks * 4 + l4) ^ (lr & 7);
                br[n * 2 + ks] = *(const f16x8*)(Bs + base + lr * 64 + slot * 8);
            }
    };

    f32x4 acc[8][4] = {};
    auto mma = [&](f16x8 (&ar)[8], f16x8 (&br)[4], int mh, int nh) {
        __builtin_amdgcn_s_setprio(1);
        #pragma unroll
        for (int m = 0; m < 4; ++m)
            #pragma unroll
            for (int n = 0; n < 2; ++n)
                #pragma unroll
                for (int ks = 0; ks < 2; ++ks)
                    acc[mh * 4 + m][nh * 2 + n] = __builtin_amdgcn_mfma_f32_16x16x32_f16(
                        ar[m * 2 + ks], br[n * 2 + ks], acc[mh * 4 + m][nh * 2 + n], 0, 0, 0);
        __builtin_amdgcn_s_setprio(0);
    };

    int NT = K >> 6, NI = NT >> 1;

    f16x8 Ar[8], B0[4], B1[4];

    // prologue: buf0 {A0,A1,B0,B1}(t0) + buf1 {B0,B1}(t1) = 12 loads;
    // vmcnt(4) drains buf0's 8 (buf1.B outstanding, drained by ph4's vmcnt).
    stageA(0, 0, 0); stageA(0, 1, 0); stageB(0, 0, 0); stageB(0, 1, 0);
    stageB(1, 0, 1); stageB(1, 1, 1);
    WAITV4(); SCHED(); BAR();

    for (int it = 0; it < NI; ++it) {
        int t1 = 2 * it + 1, t2 = 2 * it + 2, t3 = 2 * it + 3;
        if (t2 >= NT) t2 = 0;   // tail: stage into retired regions, never read
        if (t3 >= NT) t3 = 0;

        // ph1: quad(b0,mh0,nh0) | rd A(mh0),B(nh0) | stage b1.A0<-t1
        ldA(Ar, 0, 0); ldB(B0, 0, 0); stageA(1, 0, t1);
        BAR(); WAITL0(); SCHED();
        mma(Ar, B0, 0, 0); BAR();
        // ph2: quad(b0,mh0,nh1) | rd B(nh1) | stage b1.A1<-t1
        ldB(B1, 0, 1); stageA(1, 1, t1);
        BAR(); WAITL0(); SCHED();
        mma(Ar, B1, 0, 1); BAR();
        // ph3: quad(b0,mh1,nh1) | rd A(mh1) | stage b0.B0<-t2
        ldA(Ar, 0, 1); stageB(0, 0, t2);
        BAR(); WAITL0(); SCHED();
        mma(Ar, B1, 1, 1); BAR();
        // ph4: quad(b0,mh1,nh0) | no reads | stage b0.B1<-t2 | vmcnt(4)
        stageB(0, 1, t2);
        BAR(); WAITL0(); SCHED();
        mma(Ar, B0, 1, 0); WAITV4(); SCHED(); BAR();
        // ph5: quad(b1,mh0,nh0) | rd A,B | stage b0.A0<-t2
        ldA(Ar, 1, 0); ldB(B0, 1, 0); stageA(0, 0, t2);
        BAR(); WAITL0(); SCHED();
        mma(Ar, B0, 0, 0); BAR();
        // ph6: quad(b1,mh0,nh1) | rd B(nh1) | stage b0.A1<-t2
        ldB(B1, 1, 1); stageA(0, 1, t2);
        BAR(); WAITL0(); SCHED();
        mma(Ar, B1, 0, 1); BAR();
        // ph7: quad(b1,mh1,nh1) | rd A(mh1) | stage b1.B0<-t3
        ldA(Ar, 1, 1); stageB(1, 0, t3);
        BAR(); WAITL0(); SCHED();
        mma(Ar, B1, 1, 1); BAR();
        // ph8: quad(b1,mh1,nh0) | no reads | stage b1.B1<-t3 | vmcnt(2)
        stageB(1, 1, t3);
        BAR(); WAITL0(); SCHED();
        mma(Ar, B0, 1, 0); WAITV2(); SCHED(); BAR();
    }

    // epilogue: C/D layout col=lane&15, row=(lane>>4)*4+reg (m89/m91)
    #pragma unroll
    for (int nf = 0; nf < 4; ++nf) {
        int j = bn * 256 + wc * 64 + nf * 16 + l15;
        float bv = bias[j];
        #pragma unroll
        for (int mf = 0; mf < 8; ++mf) {
            int i0 = bm * 256 + wr * 128 + mf * 16 + l4 * 4;
            #pragma unroll
            for (int r = 0; r < 4; ++r) {
                float v = acc[mf][nf][r] + bv;
                if (RELU) v = fmaxf(v, 0.f);
                C[(size_t)(i0 + r) * N + j] = (f16)v;
            }
        }
    }
}

// ---- head: verified R5 128^2 kernel (Nout=10 guard, f32 out) ---------------
__global__ __launch_bounds__(256, 3) void gemm_head(
    const f16* __restrict__ A, const f16* __restrict__ B,
    const float* __restrict__ bias, float* __restrict__ C,
    int K, int Nout) {
    __shared__ f16 As[128 * 64];
    __shared__ f16 Bs[128 * 64];
    int bm = blockIdx.x;
    int t = threadIdx.x;
    int w = t >> 6, lane = t & 63;
    int wm = w >> 1, wn = w & 1;
    int l15 = lane & 15, l4 = lane >> 4;
    const f16* Ag = A + (size_t)bm * 128 * K;
    const f16* Bg = B;
    int rr = w * 8 + (lane >> 3);
    int cc = (lane & 7) * 8;
    f32x4 acc[4][4] = {};
    for (int k0 = 0; k0 < K; k0 += 64) {
        #pragma unroll
        for (int i = 0; i < 4; ++i)
            gload_lds16(Ag + (size_t)(i * 32 + rr) * K + k0 + cc, As + i * 2048 + w * 512);
        #pragma unroll
        for (int i = 0; i < 4; ++i)
            gload_lds16(Bg + (size_t)(i * 32 + rr) * K + k0 + cc, Bs + i * 2048 + w * 512);
        __syncthreads();
        #pragma unroll
        for (int ks = 0; ks < 2; ++ks) {
            f16x8 af[4], bfr[4];
            #pragma unroll
            for (int m = 0; m < 4; ++m)
                af[m] = *(const f16x8*)(As + (wm * 64 + m * 16 + l15) * 64 + ks * 32 + l4 * 8);
            #pragma unroll
            for (int n = 0; n < 4; ++n)
                bfr[n] = *(const f16x8*)(Bs + (wn * 64 + n * 16 + l15) * 64 + ks * 32 + l4 * 8);
            #pragma unroll
            for (int m = 0; m < 4; ++m)
                #pragma unroll
                for (int n = 0; n < 4; ++n)
                    acc[m][n] = __builtin_amdgcn_mfma_f32_16x16x32_f16(af[m], bfr[n], acc[m][n], 0, 0, 0);
        }
        __syncthreads();
    }
    #pragma unroll
    for (int n = 0; n < 4; ++n) {
        int j = wn * 64 + n * 16 + l15;
        bool jok = j < Nout;
        float bv = jok ? bias[j] : 0.f;
        #pragma unroll
        for (int m = 0; m < 4; ++m) {
            int i0 = bm * 128 + wm * 64 + m * 16 + l4 * 4;
            #pragma unroll
            for (int r = 0; r < 4; ++r) {
                if (jok) C[(size_t)(i0 + r) * Nout + j] = acc[m][n][r] + bv;
            }
        }
    }
}

extern "C" void kernel_launch(void* const* d_in, const int* in_sizes, int n_in,
                              void* d_out, int out_size, void* d_ws, size_t ws_size,
                              hipStream_t stream) {
    const float* x  = (const float*)d_in[0];
    const float* W1 = (const float*)d_in[1];
    const float* b1 = (const float*)d_in[2];
    const float* W2 = (const float*)d_in[3];
    const float* b2 = (const float*)d_in[4];
    const float* W3 = (const float*)d_in[5];
    const float* b3 = (const float*)d_in[6];
    const float* W4 = (const float*)d_in[7];
    const float* b4 = (const float*)d_in[8];
    const float* W5 = (const float*)d_in[9];
    const float* b5 = (const float*)d_in[10];
    const void* m1 = d_in[11];
    const void* m2 = d_in[12];
    const void* m3 = d_in[13];
    const void* m4 = d_in[14];

    char* ws = (char*)d_ws;
    size_t off = 0;
    auto alloc = [&](size_t b) { char* p = ws + off; off += (b + 255) & ~(size_t)255; return p; };
    f16* xb  = (f16*)alloc((size_t)BATCH * INDP * 2);
    f16* w1b = (f16*)alloc((size_t)HID * INDP * 2);
    f16* w2b = (f16*)alloc((size_t)HID * HID * 2);
    f16* w3b = (f16*)alloc((size_t)HID * HID * 2);
    f16* w4b = (f16*)alloc((size_t)HID * HID * 2);
    f16* w5b = (f16*)alloc((size_t)128 * HID * 2);
    f16* h1  = (f16*)alloc((size_t)BATCH * HID * 2);
    f16* h2  = (f16*)alloc((size_t)BATCH * HID * 2);

    PrepArgs pa;
    auto seg = [&](int i, const float* s, const void* mk, f16* d,
                   int rin, int kin, int kout) {
        pa.src[i] = s; pa.mk[i] = mk; pa.dst[i] = d;
        pa.rin[i] = rin; pa.kin[i] = kin; pa.kout[i] = kout;
    };
    seg(0, x,  nullptr, xb,  BATCH, IND, INDP);
    seg(1, W1, m1,      w1b, HID,   IND, INDP);
    seg(2, W2, m2,      w2b, HID,   HID, HID);
    seg(3, W3, m3,      w3b, HID,   HID, HID);
    seg(4, W4, m4,      w4b, HID,   HID, HID);
    seg(5, W5, nullptr, w5b, OUTD,  HID, HID);
    long rout[6] = {BATCH, HID, HID, HID, HID, 128};
    long acc4 = 0;
    for (int i = 0; i < 6; ++i) { pa.off4[i] = acc4; acc4 += rout[i] * (pa.kout[i] >> 2); }
    pa.off4[6] = acc4;
    int pgrid = (int)((acc4 + 255) / 256);
    prep_fused<<<pgrid, 256, 0, stream>>>(pa, acc4);

    int g8 = (BATCH / 256) * (HID / 256);   // 64 * 8 = 512 blocks
    gemm8p<true><<<g8, 512, 0, stream>>>(xb, w1b, b1, h1, HID, INDP);
    gemm8p<true><<<g8, 512, 0, stream>>>(h1, w2b, b2, h2, HID, HID);
    gemm8p<true><<<g8, 512, 0, stream>>>(h2, w3b, b3, h1, HID, HID);
    gemm8p<true><<<g8, 512, 0, stream>>>(h1, w4b, b4, h2, HID, HID);
    gemm_head<<<BATCH / 128, 256, 0, stream>>>(h2, w5b, b5, (float*)d_out, HID, OUTD);
}